// Round 9
// baseline (302.567 us; speedup 1.0000x reference)
//
#include <hip/hip_runtime.h>
#include <hip/hip_bf16.h>
#include <cstdint>

#define NB    8
#define NPTS  4096
#define NQ    4              // col-quarters (blockIdx.y)
#define NT    64             // cand tiles per quarter (1024/16)
#define PROW  64             // part row stride in u32 (4 quarters x 16)
#define SENT  0xFF000000u    // sentinel key (> any real fixed-point key)
#define KNN_T 256            // k_knn block size (4 waves)

typedef __attribute__((ext_vector_type(8))) short bf16x8;
typedef __attribute__((ext_vector_type(4))) float f32x4;

// counted vmcnt wait + scheduling fence (rule #18)
#define VWAIT(n) do { asm volatile("s_waitcnt vmcnt(" #n ")" ::: "memory"); \
                      __builtin_amdgcn_sched_barrier(0); } while (0)

// ---------------------------------------------------------------------------
// A: x [B,C,N] -> XT fp32 [B,N,64], XH/XL bf16 split, sq, sqn=128*sq+32768.
// (sqn is the 256x-scaled biased score init: 256*(0.5*sq + 128).)
// Fused: blockIdx.x==64 (y==0) builds G=[W1;W2-W1] bf16-split + BB=b1+b2.
// ---------------------------------------------------------------------------
__global__ __launch_bounds__(256) void k_prep(const float* __restrict__ x,
                                              const float* __restrict__ W1,
                                              const float* __restrict__ b1,
                                              const float* __restrict__ W2,
                                              const float* __restrict__ b2,
                                              float* __restrict__ xt,
                                              __hip_bfloat16* __restrict__ xh,
                                              __hip_bfloat16* __restrict__ xl,
                                              float* __restrict__ sq,
                                              float* __restrict__ sqn,
                                              __hip_bfloat16* __restrict__ gh,
                                              __hip_bfloat16* __restrict__ gl,
                                              float* __restrict__ bb) {
  const int t = threadIdx.x;
  if (blockIdx.x == 64) {                       // fused gsplit (one block)
    if (blockIdx.y != 0) return;
#pragma unroll 1
    for (int i = t; i < 128 * 64; i += 256) {
      int o = i >> 6, c = i & 63;
      float g = (o < 64) ? W1[o * 64 + c]
                         : (W2[(o - 64) * 64 + c] - W1[(o - 64) * 64 + c]);
      __hip_bfloat16 h = __float2bfloat16(g);
      gh[i] = h;
      gl[i] = __float2bfloat16(g - __bfloat162float(h));
    }
    if (t < 64) bb[t] = b1[t] + b2[t];
    return;
  }
  __shared__ float tile[64][65];
  const int b  = blockIdx.y;
  const int n0 = blockIdx.x * 64;
#pragma unroll
  for (int i = 0; i < 16; ++i) {
    int lin = i * 256 + t;
    int c = lin >> 6, j = lin & 63;
    tile[j][c] = x[(size_t)b * 64 * NPTS + (size_t)c * NPTS + n0 + j];
  }
  __syncthreads();
#pragma unroll
  for (int i = 0; i < 16; ++i) {
    int lin = i * 256 + t;
    int j = lin >> 6, c = lin & 63;
    float v = tile[j][c];
    size_t o = ((size_t)b * NPTS + n0 + j) * 64 + c;
    xt[o] = v;
    __hip_bfloat16 h = __float2bfloat16(v);
    xh[o] = h;
    xl[o] = __float2bfloat16(v - __bfloat162float(h));
  }
  if (t < 64) {
    float s = 0.f;
#pragma unroll
    for (int c = 0; c < 64; ++c) { float v = tile[t][c]; s = fmaf(v, v, s); }
    sq [b * NPTS + t + n0] = s;
    sqn[b * NPTS + t + n0] = fmaf(128.f, s, 32768.f);  // 256*(0.5*sq+128)
  }
}

// ---------------------------------------------------------------------------
// B: barrier-free-loop MFMA KNN (hh-only; exact rerank absorbs bf16 error).
// Score (256x-scaled, row term dropped): s = 32768 + 128*sq_m - 256*(x_r.x_m)
// > 0 always; FIXED-POINT KEY ki=(u32)s, key=(ki<<12)|m (quantum 1/128
// dist^2, 4x finer than the r1-4 float key that passed; r5 coarser FAILED).
// r9: ASYNC global->LDS PIPELINE. r1-r7 rocprof showed VGPR_Count=48: the
// compiler SINKS register prefetches to their uses -> every tile paid a
// serial L2 round trip (time pinned ~150us across all VALU/occupancy
// changes). r8's raw-asm register loads crashed (non-earlyclobber outputs
// can alias the 2nd load's address; out-of-order return clobbers it).
// Supported mechanism instead: __builtin_amdgcn_global_load_lds (async DMA,
// vmcnt-counted, no register in-flight). Depth-4 per-wave LDS ring, counted
// vmcnt(4/2/0) never 0 in-loop, sched_barrier after each wait.
// gload_lds writes base+lane*16 linearly -> swizzle applied on the GLOBAL
// source (lane loads row lane>>3, col-seg (lane&7)^row); reads at
// l15*128+((j^(l15&7))<<4) -> 2 lanes/bank = conflict-free.
// Quarter sqn staged once to LDS (kills per-tile sunk sv load).
// launch_bounds(256,4): 128-VGPR cap. DO NOT demand more waves/EU: (256,8)
// forced a 32-VGPR squeeze -> scratch spill (WRITE 8MB->544MB, 3x slower).
// ---------------------------------------------------------------------------
__global__ __launch_bounds__(KNN_T, 4) void k_knn(const __hip_bfloat16* __restrict__ xh,
                                                  const float* __restrict__ sqn,
                                                  unsigned* __restrict__ part) {
  __shared__ unsigned bufu[17 * KNN_T];           // 17.4 KB defer (slot-major)
  __shared__ float    svb[1024];                  // 4 KB: quarter sqn
  __shared__ __hip_bfloat16 stg[4][4][1024];      // 32 KB: wave x slot x tile

  const int tid  = threadIdx.x;
  const int w    = tid >> 6;                      // wave -> 16-row tile
  const int lane = tid & 63;
  const int quad = lane >> 4, l15 = lane & 15;
  const int rb   = blockIdx.x;                    // 0..63 row-block (64 rows)
  const int q    = blockIdx.y;                    // 0..3 col-quarter
  const int b    = blockIdx.z;                    // 0..7
  const size_t xbase = (size_t)b * NPTS * 64;
  const int c0   = q * 1024;
  const int nrow = rb * 64 + w * 16 + l15;        // this lane's row

  // cooperative: quarter's sqn -> LDS (1024 floats, one float4 per thread)
  *(float4*)&svb[tid * 4] = *(const float4*)(sqn + b * NPTS + c0 + tid * 4);

  // persistent B-operand fragments: the wave's rows, scaled by -256:
  // bf16 bits: ^0x8000 (negate) then +0x0400 (exponent+8 = *256).
  const __hip_bfloat16* ph = xh + xbase + (size_t)nrow * 64 + quad * 8;
  bf16x8 rh0 = *(const bf16x8*)(ph);
  bf16x8 rh1 = *(const bf16x8*)(ph + 32);
  rh0 = (rh0 ^ (short)0x8000) + (short)0x0400;
  rh1 = (rh1 ^ (short)0x8000) + (short)0x0400;

  __syncthreads();   // svb ready; also drains vmcnt before the asm pipeline

  // staging: lane covers row rw=lane>>3 (per 8-row half), col-seg (seg^rw)
  const int rw = lane >> 3, seg = lane & 7;
  const __hip_bfloat16* g0 = xh + xbase + (size_t)(c0 + rw) * 64 + (seg ^ rw) * 8;
  const __hip_bfloat16* g1 = g0 + 8 * 64;         // rows 8..15 of the tile

  auto stage = [&](int t) {                       // 2 async issues, 2 KB
    const __hip_bfloat16* s0 = g0 + (size_t)t * (16 * 64);
    const __hip_bfloat16* s1 = g1 + (size_t)t * (16 * 64);
    __hip_bfloat16* d = &stg[w][t & 3][0];
    __builtin_amdgcn_global_load_lds(
        (const __attribute__((address_space(1))) void*)s0,
        (__attribute__((address_space(3))) void*)d, 16, 0, 0);
    __builtin_amdgcn_global_load_lds(
        (const __attribute__((address_space(1))) void*)s1,
        (__attribute__((address_space(3))) void*)(d + 512), 16, 0, 0);
  };

  unsigned D[16];                                 // sorted ascending keys
#pragma unroll
  for (int i = 0; i < 16; ++i) D[i] = SENT;
  unsigned thr = SENT | 0xFFFu;
  int cnt = 0;

  auto flush = [&]() {
    unsigned E[16];
#pragma unroll
    for (int j = 0; j < 16; ++j) E[j] = bufu[j * KNN_T + tid];  // conflict-free
#pragma unroll
    for (int j = 0; j < 16; ++j) E[j] = (j < cnt) ? E[j] : 0xFFFFFFFFu;
    // bitonic full sort ascending (n=16) -- proven network
#pragma unroll
    for (int k = 2; k <= 16; k <<= 1)
#pragma unroll
      for (int j = k >> 1; j > 0; j >>= 1)
#pragma unroll
        for (int i = 0; i < 16; ++i) {
          int l = i ^ j;
          if (l > i) {
            unsigned lo = min(E[i], E[l]), hi = max(E[i], E[l]);
            bool up = ((i & k) == 0);
            E[i] = up ? lo : hi;
            E[l] = up ? hi : lo;
          }
        }
    // keep 16 smallest of D (asc) ∪ E (asc): reverse-min + bitonic clean
    unsigned T[16];
#pragma unroll
    for (int i = 0; i < 16; ++i) T[i] = min(D[i], E[15 - i]);
#pragma unroll
    for (int j = 8; j > 0; j >>= 1)
#pragma unroll
      for (int i = 0; i < 16; ++i) {
        int l = i ^ j;
        if (l > i) {
          unsigned lo = min(T[i], T[l]);
          T[l] = max(T[i], T[l]);
          T[i] = lo;
        }
      }
#pragma unroll
    for (int i = 0; i < 16; ++i) D[i] = T[i];
    cnt = 0;
    // shared threshold: min of D[15] across the row's 4 quads (rank-safe:
    // if D_q[15] < final union-16th, lane q alone holds 16 smaller keys --
    // contradiction; so discards exceed the final 16th, keeps never evicted)
    unsigned t0 = D[15] | 0xFFFu;
    unsigned t1 = min(t0, (unsigned)__shfl_xor((int)t0, 16));
    thr = min(t1, (unsigned)__shfl_xor((int)t1, 32));
  };

  // branchless insert: fixed-point key, dummy slot 16
  auto ins = [&](float s, int m) {
    unsigned ki  = (unsigned)s;                   // cvt_u32: trunc, monotone
    unsigned key = (ki << 12) | (unsigned)m;
    bool pass = (key <= thr);
    int slot = pass ? cnt : 16;
    bufu[slot * KNN_T + tid] = key;
    cnt += pass;
  };

  // swizzled read offsets (t-invariant)
  const int o0 = l15 * 128 + ((quad ^ (l15 & 7)) << 4);
  const int o1 = l15 * 128 + (((4 ^ quad) ^ (l15 & 7)) << 4);

  auto consume = [&](int t) {
    const char* tb = (const char*)&stg[w][t & 3][0];
    const bf16x8 h0 = *(const bf16x8*)(tb + o0);
    const bf16x8 h1 = *(const bf16x8*)(tb + o1);
    f32x4 m = *(const f32x4*)&svb[t * 16 + quad * 4];
    m = __builtin_amdgcn_mfma_f32_16x16x32_bf16(h0, rh0, m, 0, 0, 0);
    m = __builtin_amdgcn_mfma_f32_16x16x32_bf16(h1, rh1, m, 0, 0, 0);
    const int cb = c0 + t * 16 + quad * 4;
#pragma unroll
    for (int i = 0; i < 4; ++i) ins(m[i], cb + i);
  };

  // depth-4 ring: prologue stages 0..2; steady state waits vmcnt(4)
  // (tile t landed; t+1,t+2 in flight) then issues t+3. Tail drains 4/2/0.
  stage(0); stage(1); stage(2);
#pragma unroll 1
  for (int t = 0; t < NT - 3; ++t) {
    VWAIT(4);
    stage(t + 3);
    consume(t);
    if (__any(cnt >= 13)) flush();                // +4/tile max -> never >16
  }
  VWAIT(4); consume(NT - 3); if (__any(cnt >= 13)) flush();
  VWAIT(2); consume(NT - 2); if (__any(cnt >= 13)) flush();
  VWAIT(0); consume(NT - 1);
  flush();

  // cross-quad merge: 2 rounds of shfl_xor bitonic top-16 merging
#pragma unroll
  for (int rd = 0; rd < 2; ++rd) {
    const int dx = (rd == 0) ? 16 : 32;
    unsigned Bx[16], T[16];
#pragma unroll
    for (int i = 0; i < 16; ++i) Bx[i] = (unsigned)__shfl_xor((int)D[i], dx);
#pragma unroll
    for (int i = 0; i < 16; ++i) T[i] = min(D[i], Bx[15 - i]);
#pragma unroll
    for (int j = 8; j > 0; j >>= 1)
#pragma unroll
      for (int i = 0; i < 16; ++i) {
        int l = i ^ j;
        if (l > i) {
          unsigned lo = min(T[i], T[l]);
          T[l] = max(T[i], T[l]);
          T[i] = lo;
        }
      }
#pragma unroll
    for (int i = 0; i < 16; ++i) D[i] = T[i];
  }
  if (quad == 0) {
    const size_t base = (size_t)(b * NPTS + nrow) * PROW + (size_t)q * 16;
#pragma unroll
    for (int i = 0; i < 16; ++i) part[base + i] = D[i];
  }
}

// ---------------------------------------------------------------------------
// C+D fused: merge 64 partial keys -> top-20 (LDS handoff) -> exact fp32
// rerank -> knn[16]. 32-lane group per row, 8 rows per block. Keys are
// globally distinct (index in low 12 bits, quarter-disjoint) -> ranks
// unique, slots 0..19 exactly filled. Paired dwordx2 PART read.
// ---------------------------------------------------------------------------
__global__ __launch_bounds__(256) void k_mr(const unsigned* __restrict__ part,
                                            const float* __restrict__ xt,
                                            const float* __restrict__ sq,
                                            int* __restrict__ knn) {
  __shared__ unsigned short lc[8][20];
  const int g   = threadIdx.x >> 5;               // group 0..7
  const int c   = threadIdx.x & 31;
  const int row = blockIdx.x * 8 + g;
  // phase 1: rank 64 keys with 32 lanes (2 keys/lane, contiguous pair)
  const uint2 vv = ((const uint2*)(part + (size_t)row * PROW))[c];
  const unsigned v0 = vv.x, v1 = vv.y;
  int r0 = 0, r1 = 0;
#pragma unroll
  for (int j = 0; j < 32; ++j) {
    unsigned a = (unsigned)__shfl((int)v0, j, 32);
    unsigned d = (unsigned)__shfl((int)v1, j, 32);
    r0 += (a < v0) + (d < v0);
    r1 += (a < v1) + (d < v1);
  }
  if (r0 < 20) lc[g][r0] = (unsigned short)(v0 & 0xFFFu);
  if (r1 < 20) lc[g][r1] = (unsigned short)(v1 & 0xFFFu);
  __syncthreads();
  // phase 2: exact fp32 rerank of the 20 candidates (lanes 0..19 active)
  const int b = row >> 12;
  const int m = lc[g][c < 20 ? c : 0];
  const float4* cr = (const float4*)(xt + (size_t)row * 64);
  const float4* mr = (const float4*)(xt + ((size_t)(b << 12) + m) * 64);
  float d = 0.f;
#pragma unroll
  for (int j = 0; j < 16; ++j) {
    float4 a = cr[j], v = mr[j];
    d = fmaf(a.x, v.x, d); d = fmaf(a.y, v.y, d);
    d = fmaf(a.z, v.z, d); d = fmaf(a.w, v.w, d);
  }
  float key = sq[(b << 12) + m] - 2.f * d;          // exact fp32 rank key
  if (m == (row & 4095)) key = 1e30f;               // exclude self
  int rk = 0;
#pragma unroll
  for (int j = 0; j < 20; ++j) {
    float kj = __shfl(key, j, 32);
    int   mj = __shfl(m, j, 32);
    rk += (kj < key) || ((kj == key) && (mj < m));
  }
  if (c < 20 && rk < 16) knn[(size_t)row * 16 + rk] = m;
}

// ---------------------------------------------------------------------------
// E: MFMA P/Q GEMM. P = X·W1^T ; Q = X·(W2-W1)^T + (b1+b2), via G=[W1;W2-W1]
// bf16-split (hh+hl+lh). Wave = 16 rows x 128 outs (8 tiles, 48 MFMAs).
// ---------------------------------------------------------------------------
__global__ __launch_bounds__(256) void k_pq(const __hip_bfloat16* __restrict__ xh,
                                            const __hip_bfloat16* __restrict__ xl,
                                            const __hip_bfloat16* __restrict__ gh,
                                            const __hip_bfloat16* __restrict__ gl,
                                            const float* __restrict__ bb,
                                            float* __restrict__ P,
                                            float* __restrict__ Q) {
  const int tid  = threadIdx.x;
  const int w    = tid >> 6;
  const int lane = tid & 63;
  const int quad = lane >> 4, l15 = lane & 15;
  const int row0 = blockIdx.x * 64 + w * 16;

  const __hip_bfloat16* pa = xh + (size_t)(row0 + l15) * 64 + quad * 8;
  const __hip_bfloat16* pb = xl + (size_t)(row0 + l15) * 64 + quad * 8;
  const bf16x8 ah0 = *(const bf16x8*)(pa);
  const bf16x8 ah1 = *(const bf16x8*)(pa + 32);
  const bf16x8 al0 = *(const bf16x8*)(pb);
  const bf16x8 al1 = *(const bf16x8*)(pb + 32);

#pragma unroll
  for (int ct = 0; ct < 8; ++ct) {
    const __hip_bfloat16* qh = gh + (size_t)(ct * 16 + l15) * 64 + quad * 8;
    const __hip_bfloat16* ql = gl + (size_t)(ct * 16 + l15) * 64 + quad * 8;
    bf16x8 bh0 = *(const bf16x8*)(qh);
    bf16x8 bh1 = *(const bf16x8*)(qh + 32);
    bf16x8 bl0 = *(const bf16x8*)(ql);
    bf16x8 bl1 = *(const bf16x8*)(ql + 32);
    f32x4 m1 = { 0.f, 0.f, 0.f, 0.f };
    f32x4 m2 = m1, m3 = m1, m4 = m1, m5 = m1, m6 = m1;
    m1 = __builtin_amdgcn_mfma_f32_16x16x32_bf16(ah0, bh0, m1, 0, 0, 0);
    m2 = __builtin_amdgcn_mfma_f32_16x16x32_bf16(ah1, bh1, m2, 0, 0, 0);
    m3 = __builtin_amdgcn_mfma_f32_16x16x32_bf16(ah0, bl0, m3, 0, 0, 0);
    m4 = __builtin_amdgcn_mfma_f32_16x16x32_bf16(ah1, bl1, m4, 0, 0, 0);
    m5 = __builtin_amdgcn_mfma_f32_16x16x32_bf16(al0, bh0, m5, 0, 0, 0);
    m6 = __builtin_amdgcn_mfma_f32_16x16x32_bf16(al1, bh1, m6, 0, 0, 0);
    if (ct < 4) {
#pragma unroll
      for (int i = 0; i < 4; ++i) {
        float s = ((m1[i] + m2[i]) + (m3[i] + m4[i])) + (m5[i] + m6[i]);
        P[(size_t)(row0 + quad * 4 + i) * 64 + ct * 16 + l15] = s;
      }
    } else {
      const float bq = bb[(ct - 4) * 16 + l15];
#pragma unroll
      for (int i = 0; i < 4; ++i) {
        float s = ((m1[i] + m2[i]) + (m3[i] + m4[i])) + (m5[i] + m6[i]);
        Q[(size_t)(row0 + quad * 4 + i) * 64 + (ct - 4) * 16 + l15] = s + bq;
      }
    }
  }
}

// ---------------------------------------------------------------------------
// F: y[n][o] = relu(max_k (Q[n][o] + P[knn[n][k]][o]))
// 512 threads (8 waves x 8 rows).
// ---------------------------------------------------------------------------
__global__ __launch_bounds__(512) void k_out(const float* __restrict__ P,
                                             const float* __restrict__ Q,
                                             const int* __restrict__ knn,
                                             float* __restrict__ out) {
  __shared__ float tile[64][65];
  const int b    = blockIdx.y;
  const int n0   = blockIdx.x * 64;
  const int wave = threadIdx.x >> 6;              // 0..7
  const int lane = threadIdx.x & 63;
#pragma unroll 1
  for (int i = 0; i < 8; ++i) {
    const int nl = wave * 8 + i;
    const int gn = b * NPTS + n0 + nl;
    float acc = -1e30f;
    const float qv = Q[(size_t)gn * 64 + lane];
    const int* id = knn + (size_t)gn * 16;
#pragma unroll
    for (int k = 0; k < 16; ++k) {
      int m = id[k];
      float p = P[((size_t)b * NPTS + m) * 64 + lane];
      acc = fmaxf(acc, qv + p);
    }
    tile[nl][lane] = fmaxf(acc, 0.f);
  }
  __syncthreads();
#pragma unroll
  for (int i = 0; i < 8; ++i) {
    const int o = i * 8 + wave;
    out[((size_t)b * 64 + o) * NPTS + n0 + lane] = tile[lane][o];
  }
}

// ---------------------------------------------------------------------------
extern "C" void kernel_launch(void* const* d_in, const int* in_sizes, int n_in,
                              void* d_out, int out_size, void* d_ws, size_t ws_size,
                              hipStream_t stream) {
  const float* x  = (const float*)d_in[0];
  const float* W1 = (const float*)d_in[1];
  const float* b1 = (const float*)d_in[2];
  const float* W2 = (const float*)d_in[3];
  const float* b2 = (const float*)d_in[4];
  float* out = (float*)d_out;

  // workspace ~27.6 MB
  float* ws = (float*)d_ws;
  const size_t NPT_ALL = (size_t)NB * NPTS;                 // 32768
  float*          XT   = ws;                                // 8.39 MB
  float*          SQ   = XT + NPT_ALL * 64;                 // 0.13 MB
  float*          SQN  = SQ + NPT_ALL;                      // 0.13 MB (scaled)
  __hip_bfloat16* XH   = (__hip_bfloat16*)(SQN + NPT_ALL);  // 4.19 MB
  __hip_bfloat16* XL   = XH + NPT_ALL * 64;                 // 4.19 MB
  unsigned*       PART = (unsigned*)(XL + NPT_ALL * 64);    // 8.39 MB
  int*            KNN  = (int*)(PART + NPT_ALL * PROW);     // 2.10 MB
  __hip_bfloat16* GH   = (__hip_bfloat16*)(KNN + NPT_ALL * 16); // 16 KB
  __hip_bfloat16* GL   = GH + 128 * 64;                     // 16 KB
  float*          BB   = (float*)(GL + 128 * 64);           // 256 B
  float*          Pm   = (float*)PART;  // overlay: PART dead after k_mr
  float*          Qm   = XT;            // overlay: XT dead after k_mr (race-free)

  k_prep <<<dim3(NPTS / 64 + 1, NB), 256, 0, stream>>>(x, W1, b1, W2, b2,
                                                       XT, XH, XL, SQ, SQN,
                                                       GH, GL, BB);
  k_knn  <<<dim3(NPTS / 64, NQ, NB), KNN_T, 0, stream>>>(XH, SQN, PART);
  k_mr   <<<dim3(NPT_ALL / 8), 256, 0, stream>>>(PART, XT, SQ, KNN);
  k_pq   <<<dim3(NPT_ALL / 64), 256, 0, stream>>>(XH, XL, GH, GL, BB, Pm, Qm);
  k_out  <<<dim3(NPTS / 64, NB), 512, 0, stream>>>(Pm, Qm, KNN, out);
}

// Round 10
// 274.295 us; speedup vs baseline: 1.1031x; 1.1031x over previous
//
#include <hip/hip_runtime.h>
#include <hip/hip_bf16.h>
#include <cstdint>

#define NB    8
#define NPTS  4096
#define NQ    2              // col-halves (blockIdx.y)
#define NT    128            // cand tiles per half (2048/16)
#define PROW  32             // part row stride in u32 (2 halves x 16)
#define SENT  0xFF000000u    // sentinel key (> any real fixed-point key)
#define KNN_T 256            // k_knn block size (4 waves)

typedef __attribute__((ext_vector_type(8))) short bf16x8;
typedef __attribute__((ext_vector_type(4))) float f32x4;

// ---------------------------------------------------------------------------
// A: x [B,C,N] -> XT fp32 [B,N,64], XH/XL bf16 split, sq, sqn=128*sq+32768.
// (sqn is the 256x-scaled biased score init: 256*(0.5*sq + 128).)
// Fused: blockIdx.x==64 (y==0) builds G=[W1;W2-W1] bf16-split + BB=b1+b2.
// ---------------------------------------------------------------------------
__global__ __launch_bounds__(256) void k_prep(const float* __restrict__ x,
                                              const float* __restrict__ W1,
                                              const float* __restrict__ b1,
                                              const float* __restrict__ W2,
                                              const float* __restrict__ b2,
                                              float* __restrict__ xt,
                                              __hip_bfloat16* __restrict__ xh,
                                              __hip_bfloat16* __restrict__ xl,
                                              float* __restrict__ sq,
                                              float* __restrict__ sqn,
                                              __hip_bfloat16* __restrict__ gh,
                                              __hip_bfloat16* __restrict__ gl,
                                              float* __restrict__ bb) {
  const int t = threadIdx.x;
  if (blockIdx.x == 64) {                       // fused gsplit (one block)
    if (blockIdx.y != 0) return;
#pragma unroll 1
    for (int i = t; i < 128 * 64; i += 256) {
      int o = i >> 6, c = i & 63;
      float g = (o < 64) ? W1[o * 64 + c]
                         : (W2[(o - 64) * 64 + c] - W1[(o - 64) * 64 + c]);
      __hip_bfloat16 h = __float2bfloat16(g);
      gh[i] = h;
      gl[i] = __float2bfloat16(g - __bfloat162float(h));
    }
    if (t < 64) bb[t] = b1[t] + b2[t];
    return;
  }
  __shared__ float tile[64][65];
  const int b  = blockIdx.y;
  const int n0 = blockIdx.x * 64;
#pragma unroll
  for (int i = 0; i < 16; ++i) {
    int lin = i * 256 + t;
    int c = lin >> 6, j = lin & 63;
    tile[j][c] = x[(size_t)b * 64 * NPTS + (size_t)c * NPTS + n0 + j];
  }
  __syncthreads();
#pragma unroll
  for (int i = 0; i < 16; ++i) {
    int lin = i * 256 + t;
    int j = lin >> 6, c = lin & 63;
    float v = tile[j][c];
    size_t o = ((size_t)b * NPTS + n0 + j) * 64 + c;
    xt[o] = v;
    __hip_bfloat16 h = __float2bfloat16(v);
    xh[o] = h;
    xl[o] = __float2bfloat16(v - __bfloat162float(h));
  }
  if (t < 64) {
    float s = 0.f;
#pragma unroll
    for (int c = 0; c < 64; ++c) { float v = tile[t][c]; s = fmaf(v, v, s); }
    sq [b * NPTS + t + n0] = s;
    sqn[b * NPTS + t + n0] = fmaf(128.f, s, 32768.f);  // 256*(0.5*sq+128)
  }
}

// ---------------------------------------------------------------------------
// B: barrier-free-loop MFMA KNN (hh-only; exact rerank absorbs bf16 error).
// Score (256x-scaled, row term dropped): s = 32768 + 128*sq_m - 256*(x_r.x_m)
// > 0 always; FIXED-POINT KEY ki=(u32)s, key=(ki<<12)|m (quantum 1/128
// dist^2, 4x finer than the r1-4 float key that passed; r5 coarser FAILED).
// r10: NQ=2 COLUMN-HALVES. Rounds 1-9 proved k_knn is VALU-issue-volume
// bound (~11K instr/wave, invariant across 4 memory organizations; async
// DMA pipeline r9 changed nothing). Selection machinery dominates. Halving
// the partition count: waves halve (fixed costs/2 in total), selection
// passes/row 328 -> 188 (flush work ~/2), PART 64 -> 32 keys (k_mr /2).
// Selection/key/flush logic byte-identical to r9 (passed). Half's sqn
// staged once in LDS. Simple register loads (memory org proven irrelevant).
// launch_bounds(256,4): 128-VGPR cap. DO NOT demand more waves/EU: (256,8)
// forced a 32-VGPR squeeze -> scratch spill (WRITE 8MB->544MB, 3x slower).
// ---------------------------------------------------------------------------
struct Frag { bf16x8 h0, h1; f32x4 sv; };

__global__ __launch_bounds__(KNN_T, 4) void k_knn(const __hip_bfloat16* __restrict__ xh,
                                                  const float* __restrict__ sqn,
                                                  unsigned* __restrict__ part) {
  __shared__ unsigned bufu[17 * KNN_T];           // 17.4 KB defer (slot-major)
  __shared__ float    svb[2048];                  // 8 KB: half's sqn

  const int tid  = threadIdx.x;
  const int w    = tid >> 6;                      // wave -> 16-row tile
  const int lane = tid & 63;
  const int quad = lane >> 4, l15 = lane & 15;
  const int rb   = blockIdx.x;                    // 0..63 row-block (64 rows)
  const int q    = blockIdx.y;                    // 0..1 col-half
  const int b    = blockIdx.z;                    // 0..7
  const size_t xbase = (size_t)b * NPTS * 64;
  const int c0   = q * 2048;
  const int nrow = rb * 64 + w * 16 + l15;        // this lane's row

  // cooperative: half's sqn -> LDS (2048 floats, two float4 per thread)
  {
    const float4* src = (const float4*)(sqn + b * NPTS + c0);
    ((float4*)svb)[tid]       = src[tid];
    ((float4*)svb)[tid + 256] = src[tid + 256];
  }

  // persistent B-operand fragments: the wave's rows, scaled by -256:
  // bf16 bits: ^0x8000 (negate) then +0x0400 (exponent+8 = *256).
  const __hip_bfloat16* ph = xh + xbase + (size_t)nrow * 64 + quad * 8;
  bf16x8 rh0 = *(const bf16x8*)(ph);
  bf16x8 rh1 = *(const bf16x8*)(ph + 32);
  rh0 = (rh0 ^ (short)0x8000) + (short)0x0400;
  rh1 = (rh1 ^ (short)0x8000) + (short)0x0400;

  __syncthreads();                                // svb ready (only barrier)

  unsigned D[16];                                 // sorted ascending keys
#pragma unroll
  for (int i = 0; i < 16; ++i) D[i] = SENT;
  unsigned thr = SENT | 0xFFFu;
  int cnt = 0;

  auto ldfrag = [&](int t) -> Frag {
    Frag f;
    const __hip_bfloat16* ah = xh + xbase + (size_t)(c0 + t * 16 + l15) * 64 + quad * 8;
    f.h0 = *(const bf16x8*)(ah);
    f.h1 = *(const bf16x8*)(ah + 32);
    f.sv = *(const f32x4*)&svb[t * 16 + quad * 4];
    return f;
  };

  auto flush = [&]() {
    unsigned E[16];
#pragma unroll
    for (int j = 0; j < 16; ++j) E[j] = bufu[j * KNN_T + tid];  // conflict-free
#pragma unroll
    for (int j = 0; j < 16; ++j) E[j] = (j < cnt) ? E[j] : 0xFFFFFFFFu;
    // bitonic full sort ascending (n=16) -- proven network
#pragma unroll
    for (int k = 2; k <= 16; k <<= 1)
#pragma unroll
      for (int j = k >> 1; j > 0; j >>= 1)
#pragma unroll
        for (int i = 0; i < 16; ++i) {
          int l = i ^ j;
          if (l > i) {
            unsigned lo = min(E[i], E[l]), hi = max(E[i], E[l]);
            bool up = ((i & k) == 0);
            E[i] = up ? lo : hi;
            E[l] = up ? hi : lo;
          }
        }
    // keep 16 smallest of D (asc) ∪ E (asc): reverse-min + bitonic clean
    unsigned T[16];
#pragma unroll
    for (int i = 0; i < 16; ++i) T[i] = min(D[i], E[15 - i]);
#pragma unroll
    for (int j = 8; j > 0; j >>= 1)
#pragma unroll
      for (int i = 0; i < 16; ++i) {
        int l = i ^ j;
        if (l > i) {
          unsigned lo = min(T[i], T[l]);
          T[l] = max(T[i], T[l]);
          T[i] = lo;
        }
      }
#pragma unroll
    for (int i = 0; i < 16; ++i) D[i] = T[i];
    cnt = 0;
    // shared threshold: min of D[15] across the row's 4 quads (rank-safe:
    // if D_q[15] < final union-16th, lane q alone holds 16 smaller keys --
    // contradiction; so discards exceed the final 16th, keeps never evicted)
    unsigned t0 = D[15] | 0xFFFu;
    unsigned t1 = min(t0, (unsigned)__shfl_xor((int)t0, 16));
    thr = min(t1, (unsigned)__shfl_xor((int)t1, 32));
  };

  // branchless insert: fixed-point key, dummy slot 16
  auto ins = [&](float s, int m) {
    unsigned ki  = (unsigned)s;                   // cvt_u32: trunc, monotone
    unsigned key = (ki << 12) | (unsigned)m;
    bool pass = (key <= thr);
    int slot = pass ? cnt : 16;
    bufu[slot * KNN_T + tid] = key;
    cnt += pass;
  };

  // chained K-half MFMAs for 2 tiles (independent chains); C-init = sv
  auto compute2 = [&](const Frag& fa, const Frag& fb, int tbase) {
    f32x4 m1 = fa.sv, m3 = fb.sv;
    m1 = __builtin_amdgcn_mfma_f32_16x16x32_bf16(fa.h0, rh0, m1, 0, 0, 0);
    m3 = __builtin_amdgcn_mfma_f32_16x16x32_bf16(fb.h0, rh0, m3, 0, 0, 0);
    m1 = __builtin_amdgcn_mfma_f32_16x16x32_bf16(fa.h1, rh1, m1, 0, 0, 0);
    m3 = __builtin_amdgcn_mfma_f32_16x16x32_bf16(fb.h1, rh1, m3, 0, 0, 0);
    const int ca = c0 + tbase * 16 + quad * 4;
#pragma unroll
    for (int i = 0; i < 4; ++i) ins(m1[i], ca + i);
#pragma unroll
    for (int i = 0; i < 4; ++i) ins(m3[i], ca + 16 + i);
  };

  Frag a0 = ldfrag(0), a1 = ldfrag(1);
#pragma unroll 1
  for (int it = 0; it < NT / 4; ++it) {
    const int t4 = it * 4;
    Frag b0 = ldfrag(t4 + 2), b1 = ldfrag(t4 + 3);
    compute2(a0, a1, t4);
    if (__any(cnt >= 9)) flush();                 // +8 max/step -> never >16
    const int tn = (t4 + 4 < NT) ? t4 + 4 : NT - 2;  // clamp: last prefetch dead
    a0 = ldfrag(tn);
    a1 = ldfrag(tn + 1);
    compute2(b0, b1, t4 + 2);
    if (__any(cnt >= 9)) flush();
  }
  flush();

  // cross-quad merge: 2 rounds of shfl_xor bitonic top-16 merging
#pragma unroll
  for (int rd = 0; rd < 2; ++rd) {
    const int dx = (rd == 0) ? 16 : 32;
    unsigned Bx[16], T[16];
#pragma unroll
    for (int i = 0; i < 16; ++i) Bx[i] = (unsigned)__shfl_xor((int)D[i], dx);
#pragma unroll
    for (int i = 0; i < 16; ++i) T[i] = min(D[i], Bx[15 - i]);
#pragma unroll
    for (int j = 8; j > 0; j >>= 1)
#pragma unroll
      for (int i = 0; i < 16; ++i) {
        int l = i ^ j;
        if (l > i) {
          unsigned lo = min(T[i], T[l]);
          T[l] = max(T[i], T[l]);
          T[i] = lo;
        }
      }
#pragma unroll
    for (int i = 0; i < 16; ++i) D[i] = T[i];
  }
  if (quad == 0) {
    const size_t base = (size_t)(b * NPTS + nrow) * PROW + (size_t)q * 16;
#pragma unroll
    for (int i = 0; i < 16; ++i) part[base + i] = D[i];
  }
}

// ---------------------------------------------------------------------------
// C+D fused: merge 32 partial keys -> top-20 (LDS handoff) -> exact fp32
// rerank -> knn[16]. 32-lane group per row (1 key/lane), 8 rows per block.
// Keys globally distinct (index in low 12 bits, halves disjoint) -> ranks
// unique, slots 0..19 exactly filled.
// ---------------------------------------------------------------------------
__global__ __launch_bounds__(256) void k_mr(const unsigned* __restrict__ part,
                                            const float* __restrict__ xt,
                                            const float* __restrict__ sq,
                                            int* __restrict__ knn) {
  __shared__ unsigned short lc[8][20];
  const int g   = threadIdx.x >> 5;               // group 0..7
  const int c   = threadIdx.x & 31;
  const int row = blockIdx.x * 8 + g;
  // phase 1: rank 32 keys with 32 lanes (1 key/lane)
  const unsigned v = part[(size_t)row * PROW + c];
  int r = 0;
#pragma unroll
  for (int j = 0; j < 32; ++j) {
    unsigned a = (unsigned)__shfl((int)v, j, 32);
    r += (a < v);
  }
  if (r < 20) lc[g][r] = (unsigned short)(v & 0xFFFu);
  __syncthreads();
  // phase 2: exact fp32 rerank of the 20 candidates (lanes 0..19 active)
  const int b = row >> 12;
  const int m = lc[g][c < 20 ? c : 0];
  const float4* cr = (const float4*)(xt + (size_t)row * 64);
  const float4* mr = (const float4*)(xt + ((size_t)(b << 12) + m) * 64);
  float d = 0.f;
#pragma unroll
  for (int j = 0; j < 16; ++j) {
    float4 a = cr[j], vv = mr[j];
    d = fmaf(a.x, vv.x, d); d = fmaf(a.y, vv.y, d);
    d = fmaf(a.z, vv.z, d); d = fmaf(a.w, vv.w, d);
  }
  float key = sq[(b << 12) + m] - 2.f * d;          // exact fp32 rank key
  if (m == (row & 4095)) key = 1e30f;               // exclude self
  int rk = 0;
#pragma unroll
  for (int j = 0; j < 20; ++j) {
    float kj = __shfl(key, j, 32);
    int   mj = __shfl(m, j, 32);
    rk += (kj < key) || ((kj == key) && (mj < m));
  }
  if (c < 20 && rk < 16) knn[(size_t)row * 16 + rk] = m;
}

// ---------------------------------------------------------------------------
// E: MFMA P/Q GEMM. P = X·W1^T ; Q = X·(W2-W1)^T + (b1+b2), via G=[W1;W2-W1]
// bf16-split (hh+hl+lh). Wave = 16 rows x 128 outs (8 tiles, 48 MFMAs).
// ---------------------------------------------------------------------------
__global__ __launch_bounds__(256) void k_pq(const __hip_bfloat16* __restrict__ xh,
                                            const __hip_bfloat16* __restrict__ xl,
                                            const __hip_bfloat16* __restrict__ gh,
                                            const __hip_bfloat16* __restrict__ gl,
                                            const float* __restrict__ bb,
                                            float* __restrict__ P,
                                            float* __restrict__ Q) {
  const int tid  = threadIdx.x;
  const int w    = tid >> 6;
  const int lane = tid & 63;
  const int quad = lane >> 4, l15 = lane & 15;
  const int row0 = blockIdx.x * 64 + w * 16;

  const __hip_bfloat16* pa = xh + (size_t)(row0 + l15) * 64 + quad * 8;
  const __hip_bfloat16* pb = xl + (size_t)(row0 + l15) * 64 + quad * 8;
  const bf16x8 ah0 = *(const bf16x8*)(pa);
  const bf16x8 ah1 = *(const bf16x8*)(pa + 32);
  const bf16x8 al0 = *(const bf16x8*)(pb);
  const bf16x8 al1 = *(const bf16x8*)(pb + 32);

#pragma unroll
  for (int ct = 0; ct < 8; ++ct) {
    const __hip_bfloat16* qh = gh + (size_t)(ct * 16 + l15) * 64 + quad * 8;
    const __hip_bfloat16* ql = gl + (size_t)(ct * 16 + l15) * 64 + quad * 8;
    bf16x8 bh0 = *(const bf16x8*)(qh);
    bf16x8 bh1 = *(const bf16x8*)(qh + 32);
    bf16x8 bl0 = *(const bf16x8*)(ql);
    bf16x8 bl1 = *(const bf16x8*)(ql + 32);
    f32x4 m1 = { 0.f, 0.f, 0.f, 0.f };
    f32x4 m2 = m1, m3 = m1, m4 = m1, m5 = m1, m6 = m1;
    m1 = __builtin_amdgcn_mfma_f32_16x16x32_bf16(ah0, bh0, m1, 0, 0, 0);
    m2 = __builtin_amdgcn_mfma_f32_16x16x32_bf16(ah1, bh1, m2, 0, 0, 0);
    m3 = __builtin_amdgcn_mfma_f32_16x16x32_bf16(ah0, bl0, m3, 0, 0, 0);
    m4 = __builtin_amdgcn_mfma_f32_16x16x32_bf16(ah1, bl1, m4, 0, 0, 0);
    m5 = __builtin_amdgcn_mfma_f32_16x16x32_bf16(al0, bh0, m5, 0, 0, 0);
    m6 = __builtin_amdgcn_mfma_f32_16x16x32_bf16(al1, bh1, m6, 0, 0, 0);
    if (ct < 4) {
#pragma unroll
      for (int i = 0; i < 4; ++i) {
        float s = ((m1[i] + m2[i]) + (m3[i] + m4[i])) + (m5[i] + m6[i]);
        P[(size_t)(row0 + quad * 4 + i) * 64 + ct * 16 + l15] = s;
      }
    } else {
      const float bq = bb[(ct - 4) * 16 + l15];
#pragma unroll
      for (int i = 0; i < 4; ++i) {
        float s = ((m1[i] + m2[i]) + (m3[i] + m4[i])) + (m5[i] + m6[i]);
        Q[(size_t)(row0 + quad * 4 + i) * 64 + (ct - 4) * 16 + l15] = s + bq;
      }
    }
  }
}

// ---------------------------------------------------------------------------
// F: y[n][o] = relu(max_k (Q[n][o] + P[knn[n][k]][o]))
// 512 threads (8 waves x 8 rows).
// ---------------------------------------------------------------------------
__global__ __launch_bounds__(512) void k_out(const float* __restrict__ P,
                                             const float* __restrict__ Q,
                                             const int* __restrict__ knn,
                                             float* __restrict__ out) {
  __shared__ float tile[64][65];
  const int b    = blockIdx.y;
  const int n0   = blockIdx.x * 64;
  const int wave = threadIdx.x >> 6;              // 0..7
  const int lane = threadIdx.x & 63;
#pragma unroll 1
  for (int i = 0; i < 8; ++i) {
    const int nl = wave * 8 + i;
    const int gn = b * NPTS + n0 + nl;
    float acc = -1e30f;
    const float qv = Q[(size_t)gn * 64 + lane];
    const int* id = knn + (size_t)gn * 16;
#pragma unroll
    for (int k = 0; k < 16; ++k) {
      int m = id[k];
      float p = P[((size_t)b * NPTS + m) * 64 + lane];
      acc = fmaxf(acc, qv + p);
    }
    tile[nl][lane] = fmaxf(acc, 0.f);
  }
  __syncthreads();
#pragma unroll
  for (int i = 0; i < 8; ++i) {
    const int o = i * 8 + wave;
    out[((size_t)b * 64 + o) * NPTS + n0 + lane] = tile[lane][o];
  }
}

// ---------------------------------------------------------------------------
extern "C" void kernel_launch(void* const* d_in, const int* in_sizes, int n_in,
                              void* d_out, int out_size, void* d_ws, size_t ws_size,
                              hipStream_t stream) {
  const float* x  = (const float*)d_in[0];
  const float* W1 = (const float*)d_in[1];
  const float* b1 = (const float*)d_in[2];
  const float* W2 = (const float*)d_in[3];
  const float* b2 = (const float*)d_in[4];
  float* out = (float*)d_out;

  // workspace ~27.6 MB (PART region kept at 64 u32/row so Pm overlay fits)
  float* ws = (float*)d_ws;
  const size_t NPT_ALL = (size_t)NB * NPTS;                 // 32768
  float*          XT   = ws;                                // 8.39 MB
  float*          SQ   = XT + NPT_ALL * 64;                 // 0.13 MB
  float*          SQN  = SQ + NPT_ALL;                      // 0.13 MB (scaled)
  __hip_bfloat16* XH   = (__hip_bfloat16*)(SQN + NPT_ALL);  // 4.19 MB
  __hip_bfloat16* XL   = XH + NPT_ALL * 64;                 // 4.19 MB
  unsigned*       PART = (unsigned*)(XL + NPT_ALL * 64);    // 8.39 MB region
  int*            KNN  = (int*)(PART + NPT_ALL * 64);       // 2.10 MB
  __hip_bfloat16* GH   = (__hip_bfloat16*)(KNN + NPT_ALL * 16); // 16 KB
  __hip_bfloat16* GL   = GH + 128 * 64;                     // 16 KB
  float*          BB   = (float*)(GL + 128 * 64);           // 256 B
  float*          Pm   = (float*)PART;  // overlay: PART dead after k_mr
  float*          Qm   = XT;            // overlay: XT dead after k_mr (race-free)

  k_prep <<<dim3(NPTS / 64 + 1, NB), 256, 0, stream>>>(x, W1, b1, W2, b2,
                                                       XT, XH, XL, SQ, SQN,
                                                       GH, GL, BB);
  k_knn  <<<dim3(NPTS / 64, NQ, NB), KNN_T, 0, stream>>>(XH, SQN, PART);
  k_mr   <<<dim3(NPT_ALL / 8), 256, 0, stream>>>(PART, XT, SQ, KNN);
  k_pq   <<<dim3(NPT_ALL / 64), 256, 0, stream>>>(XH, XL, GH, GL, BB, Pm, Qm);
  k_out  <<<dim3(NPTS / 64, NB), 512, 0, stream>>>(Pm, Qm, KNN, out);
}